// Round 2
// baseline (99.114 us; speedup 1.0000x reference)
//
#include <hip/hip_runtime.h>
#include <stdint.h>

// Problem: B=1,000,000 rows; IN=64, H=128, OUT=2, 3 heads, per-row routing u in [0,3).
// out[b,:] = Wb[u[b]] @ relu(W1 @ x[b] + b1) + bb[u[b]]

typedef float f32x4 __attribute__((ext_vector_type(4)));
typedef int   i32x4 __attribute__((ext_vector_type(4)));
typedef short short8 __attribute__((ext_vector_type(8)));
typedef __bf16 bf16x8 __attribute__((ext_vector_type(8)));

// f32 -> bf16 bits, round-to-nearest-even
static __device__ __forceinline__ short f2bf(float f) {
    uint32_t x = __builtin_bit_cast(uint32_t, f);
    x += 0x7fffu + ((x >> 16) & 1u);
    return (short)(x >> 16);
}

static __device__ __forceinline__ f32x4 mfma16(short8 a, short8 b, f32x4 c) {
    return __builtin_amdgcn_mfma_f32_16x16x32_bf16(
        __builtin_bit_cast(bf16x8, a), __builtin_bit_cast(bf16x8, b), c, 0, 0, 0);
}

// One wave processes one 16-row batch tile per iteration.
// Trunk: h^T[128 x 16] = W1[128x64] @ x^T[64x16]  (A = W1 from LDS, B = x from global)
//   MFMA k-packing bijection (per K=32 step s): k = 8*gamma + j   (gamma = lane>>4)
//   C layout: lane holds rows 4*gamma+r (r=reg), col = lane&15 = batch row.
//   => lane `l` holds h[batch = base + (l&15)][n = 16t + 4*gamma + r] for t=0..7.
// Head: out_all[16 x 6] = relu(h)[16x128] @ Wb_all^T[128x6]
//   A2 row = lane&15 = batch row (matches trunk layout -- no cross-lane movement).
//   k-packing bijection per step: n = 32s + 16*(j>>2) + 4*gamma + (j&3), which is exactly
//   the n-set the lane already holds (t = 2s + (j>>2), r = j&3).
//   C2: lane holds batch rows 4*gamma+r, col = lane&15 = head*2+out combo (0..5 valid).
__global__ __launch_bounds__(256) void coil_fused(
    const float* __restrict__ x,
    const int*   __restrict__ u,    // routing ids, int32 on device
    const float* __restrict__ W1,
    const float* __restrict__ b1,
    const float* __restrict__ Wb,   // [3][2][128]
    const float* __restrict__ bb,   // [3][2]
    float* __restrict__ out,        // [B][2]
    int nTiles, int totalWaves)
{
    __shared__ short w1s[128 * 64];   // bf16 bits, XOR-swizzled rows (16 KiB)
    __shared__ float b1s[128];

    const int tid  = threadIdx.x;
    const int lane = tid & 63;
    const int c    = lane & 15;       // "parallel" index within MFMA
    const int g    = lane >> 4;       // k-group gamma

    // ---- stage W1 into LDS as bf16, swizzled: phys = logical ^ ((row&7)<<4) ----
    // 128 rows x 64 bf16 = 1024 chunks of 16 B (8 chunks per row).
    for (int q = tid; q < 1024; q += 256) {
        int row = q >> 3;
        const float* src = W1 + row * 64 + (q & 7) * 8;
        short8 v;
        #pragma unroll
        for (int j = 0; j < 8; ++j) v[j] = f2bf(src[j]);
        int phys = (q * 16) ^ ((row & 7) << 4);
        *reinterpret_cast<short8*>(reinterpret_cast<char*>(w1s) + phys) = v;
    }
    if (tid < 128) b1s[tid] = b1[tid];

    // ---- loop-invariant head-weight fragments (Wb) + head bias, per lane ----
    const int ko = c;                  // combo = head*2 + out_pos; valid if < 6
    const bool kvalid = (ko < 6);
    short8 B2[4];
    #pragma unroll
    for (int s = 0; s < 4; ++s) {
        #pragma unroll
        for (int j = 0; j < 8; ++j) {
            int n = 32 * s + ((j >> 2) << 4) + 4 * g + (j & 3);
            B2[s][j] = kvalid ? f2bf(Wb[ko * 128 + n]) : (short)0;
        }
    }
    const float bbr = kvalid ? bb[ko] : 0.0f;

    __syncthreads();

    const int wave = blockIdx.x * (blockDim.x >> 6) + (tid >> 6);
    const char* w1bytes = reinterpret_cast<const char*>(w1s);
    const int sw = (c & 7) << 4;
    const int khead = ko >> 1, opos = ko & 1;

    for (int tile = wave; tile < nTiles; tile += totalWaves) {
        const int base = tile << 4;

        // x fragments: this lane's batch row = base + c; k = 32s + 8g + j
        const float* xr = x + (base + c) * 64 + 8 * g;
        f32x4 xa = *reinterpret_cast<const f32x4*>(xr);       // s=0, j=0..3
        f32x4 xb = *reinterpret_cast<const f32x4*>(xr + 4);   // s=0, j=4..7
        f32x4 xc = *reinterpret_cast<const f32x4*>(xr + 32);  // s=1, j=0..3
        f32x4 xd = *reinterpret_cast<const f32x4*>(xr + 36);  // s=1, j=4..7

        // routing ids for the 4 batch rows this lane will hold after the head MFMA
        const int m0 = base + 4 * g;
        i32x4 uv = *reinterpret_cast<const i32x4*>(u + m0);   // 16B-aligned (m0 % 4 == 0)

        short8 B1a, B1b;
        #pragma unroll
        for (int j = 0; j < 4; ++j) {
            B1a[j] = f2bf(xa[j]); B1a[4 + j] = f2bf(xb[j]);
            B1b[j] = f2bf(xc[j]); B1b[4 + j] = f2bf(xd[j]);
        }

        // ---- trunk: 8 h-tiles, bias-seeded accumulators ----
        f32x4 h[8];
        #pragma unroll
        for (int t = 0; t < 8; ++t) {
            f32x4 acc = *reinterpret_cast<const f32x4*>(&b1s[16 * t + 4 * g]); // broadcast
            int lo = (16 * t + c) * 128 + 16 * g;     // logical byte offset, s=0
            short8 A0 = *reinterpret_cast<const short8*>(w1bytes + (lo ^ sw));
            short8 A1 = *reinterpret_cast<const short8*>(w1bytes + ((lo + 64) ^ sw));
            acc = mfma16(A0, B1a, acc);
            acc = mfma16(A1, B1b, acc);
            h[t] = acc;
        }

        // ---- head: relu + pack + 4 MFMAs over K=128 ----
        f32x4 oacc = {0.f, 0.f, 0.f, 0.f};
        #pragma unroll
        for (int s = 0; s < 4; ++s) {
            short8 A2;
            #pragma unroll
            for (int j = 0; j < 8; ++j) {
                float v = h[2 * s + (j >> 2)][j & 3];
                A2[j] = f2bf(fmaxf(v, 0.0f));
            }
            oacc = mfma16(A2, B2[s], oacc);
        }

        // ---- select head per row and store (each output element hits exactly 1 lane) ----
        if (khead == uv[0]) out[(m0 + 0) * 2 + opos] = oacc[0] + bbr;
        if (khead == uv[1]) out[(m0 + 1) * 2 + opos] = oacc[1] + bbr;
        if (khead == uv[2]) out[(m0 + 2) * 2 + opos] = oacc[2] + bbr;
        if (khead == uv[3]) out[(m0 + 3) * 2 + opos] = oacc[3] + bbr;
    }
}

extern "C" void kernel_launch(void* const* d_in, const int* in_sizes, int n_in,
                              void* d_out, int out_size, void* d_ws, size_t ws_size,
                              hipStream_t stream) {
    const float* x  = (const float*)d_in[0];
    const int*   u  = (const int*)d_in[1];   // integer inputs are int32 on device
    const float* W1 = (const float*)d_in[2];
    const float* b1 = (const float*)d_in[3];
    const float* Wb = (const float*)d_in[4];
    const float* bb = (const float*)d_in[5];
    float* out = (float*)d_out;

    const int B = in_sizes[1];        // u has one element per row
    const int nTiles = B / 16;        // B = 1,000,000 -> 62,500 (exact)

    int blocks = 2048;                // 4 waves/block, grid-stride ~7.6 tiles/wave
    int totalWaves = blocks * 4;
    if (totalWaves > nTiles) { blocks = (nTiles + 3) / 4; totalWaves = blocks * 4; }

    hipLaunchKernelGGL(coil_fused, dim3(blocks), dim3(256), 0, stream,
                       x, u, W1, b1, Wb, bb, out, nTiles, totalWaves);
}